// Round 14
// baseline (386.690 us; speedup 1.0000x reference)
//
#include <hip/hip_runtime.h>
#include <math.h>

#define VOCABN 100000
#define EMBD 300
#define HID 128
#define NQ 32
#define NTOP 10

#define NCHS 19             // chunks scored, 16 k each (k 0..303, tail zero-padded)
#define NCHT 20             // chunks in W fragment table
#define CMIN 3
#define CAPA 43691          // pigeonhole max rows with count>=3 (131072/3)
#define NBLK 256            // k_mega: 1-wave blocks, 1/CU guaranteed resident
#define GRID_F ((VOCABN + 31) / 32)   // 3125 dense tiles

typedef __attribute__((ext_vector_type(8))) short bf16x8;
typedef __attribute__((ext_vector_type(4))) float f32x4;
typedef __attribute__((ext_vector_type(16))) float f32x16;
typedef __attribute__((ext_vector_type(4))) unsigned int u32x4;

__device__ __forceinline__ void split8(const f32x4 a, const f32x4 b,
                                       u32x4* hi, u32x4* lo) {
    float ef[8] = {a.x, a.y, a.z, a.w, b.x, b.y, b.z, b.w};
    unsigned int hw[8], lw[8];
#pragma unroll
    for (int j = 0; j < 8; ++j) {
        unsigned int u = __float_as_uint(ef[j]);
        hw[j] = u >> 16;
        float r = __uint_as_float(u & 0xffff0000u);
        lw[j] = __float_as_uint(ef[j] - r) >> 16;
    }
    *hi = (u32x4){hw[0] | (hw[1] << 16), hw[2] | (hw[3] << 16),
                  hw[4] | (hw[5] << 16), hw[6] | (hw[7] << 16)};
    *lo = (u32x4){lw[0] | (lw[1] << 16), lw[2] | (lw[3] << 16),
                  lw[4] | (lw[5] << 16), lw[6] | (lw[7] << 16)};
}

__device__ __forceinline__ bool tbetter(float w1, int i1, float w2, int i2) {
    return w1 > w2 || (w1 == w2 && i1 < i2);
}

__device__ __forceinline__ void lds_insert(float* mw, int* mid, int t, float w, int id) {
    const int b = t * NTOP;
    if (!tbetter(w, id, mw[b + NTOP - 1], mid[b + NTOP - 1])) return;
    int p = NTOP - 1;
    while (p > 0 && tbetter(w, id, mw[b + p - 1], mid[b + p - 1])) {
        mw[b + p] = mw[b + p - 1]; mid[b + p] = mid[b + p - 1]; --p;
    }
    mw[b + p] = w; mid[b + p] = id;
}

// device-scope grid barrier (validated round 13: absmax 0.0 across 6 phases)
__device__ __forceinline__ void gbar(int* ctr, int phase) {
    __syncthreads();
    if (threadIdx.x == 0) {
        __threadfence();
        atomicAdd(ctr, 1);
        const int tgt = NBLK * phase;
        while (__hip_atomic_load(ctr, __ATOMIC_ACQUIRE, __HIP_MEMORY_SCOPE_AGENT) < tgt)
            __builtin_amdgcn_s_sleep(8);
        __threadfence();
    }
    __syncthreads();
}

// per-wave 32-row x 128-col bf16x3 MFMA scorer (proven r7/r12 standalone: 72 VGPR, no spill)
__device__ void score_tiles(int gw, int nwaves, const float* __restrict__ emb,
                            const unsigned short* __restrict__ wfH,
                            const unsigned short* __restrict__ wfL,
                            const float* __restrict__ qcbp,
                            const float* __restrict__ w2p, float b2,
                            const int* __restrict__ cand,
                            const int* __restrict__ ccnt,
                            const int* __restrict__ counts, int ncand,
                            float* __restrict__ taw, int* __restrict__ tai,
                            float* pvrow) {
    const int lane = threadIdx.x & 63;
    const int lrow = lane & 31;
    const int khalf = lane >> 5;
    const int ntile = (ncand + 31) >> 5;

    float qv[4], w2v[4];
#pragma unroll
    for (int t = 0; t < 4; ++t) {
        qv[t] = qcbp[t * 32 + lrow];
        w2v[t] = w2p[t * 32 + lrow];
    }

    for (int tile = gw; tile < ntile; tile += nwaves) {
        const int base = tile * 32;
        int ri = base + lrow;
        int rc = ri < ncand ? ri : ncand - 1;
        const long row = cand ? (long)cand[rc] : (long)rc;
        const float* ebase = emb + row * EMBD;

        f32x16 acc[4];
#pragma unroll
        for (int t = 0; t < 4; ++t)
#pragma unroll
            for (int r = 0; r < 16; ++r) acc[t][r] = 0.f;

        f32x4 e0[3], e1[3];
        u32x4 wh[3][4], wl[3][4];
        const f32x4 zf4 = (f32x4){0.f, 0.f, 0.f, 0.f};

#define LOADC(NN, S)                                                         \
    { int nn_ = (NN);                                                        \
      if (nn_ < NCHS) {                                                      \
          int k0_ = nn_ * 16 + khalf * 8;                                    \
          e0[S] = (k0_ + 4 <= EMBD) ? *(const f32x4*)(ebase + k0_) : zf4;    \
          e1[S] = (k0_ + 8 <= EMBD) ? *(const f32x4*)(ebase + k0_ + 4) : zf4;\
          _Pragma("unroll")                                                  \
          for (int t_ = 0; t_ < 4; ++t_) {                                   \
              long fo_ = ((long)(nn_ * 4 + t_) * 64 + lane) * 8;             \
              wh[S][t_] = *(const u32x4*)&wfH[fo_];                          \
              wl[S][t_] = *(const u32x4*)&wfL[fo_];                          \
          } } }

#define COMP(CC, S)                                                          \
    { if ((CC) < NCHS) {                                                     \
          union { bf16x8 v; u32x4 u; } eh_, el_;                             \
          split8(e0[S], e1[S], &eh_.u, &el_.u);                              \
          _Pragma("unroll")                                                  \
          for (int t_ = 0; t_ < 4; ++t_) {                                   \
              union { bf16x8 v; u32x4 u; } bh_, bl_;                         \
              bh_.u = wh[S][t_]; bl_.u = wl[S][t_];                          \
              acc[t_] = __builtin_amdgcn_mfma_f32_32x32x16_bf16(eh_.v, bh_.v, acc[t_], 0, 0, 0); \
              acc[t_] = __builtin_amdgcn_mfma_f32_32x32x16_bf16(eh_.v, bl_.v, acc[t_], 0, 0, 0); \
              acc[t_] = __builtin_amdgcn_mfma_f32_32x32x16_bf16(el_.v, bh_.v, acc[t_], 0, 0, 0); \
          } } }

        LOADC(0, 0) LOADC(1, 1) LOADC(2, 2)
        for (int g = 0; g < 7; ++g) {
            int c = g * 3;
            COMP(c + 0, 0) LOADC(c + 3, 0)
            COMP(c + 1, 1) LOADC(c + 4, 1)
            COMP(c + 2, 2) LOADC(c + 5, 2)
        }
#undef LOADC
#undef COMP

        float pr[16];
#pragma unroll
        for (int r = 0; r < 16; ++r) {
            float s = 0.f;
#pragma unroll
            for (int t = 0; t < 4; ++t) {
                float h = fmaxf(acc[t][r] + qv[t], 0.f);
                s += h * w2v[t];
            }
            s += __shfl_xor(s, 1); s += __shfl_xor(s, 2);
            s += __shfl_xor(s, 4); s += __shfl_xor(s, 8);
            s += __shfl_xor(s, 16);
            pr[r] = s;
        }
        if (lrow == 0) {
#pragma unroll
            for (int r = 0; r < 16; ++r)
                pvrow[(r & 3) + 8 * (r >> 2) + 4 * khalf] = pr[r];
        }
        asm volatile("s_waitcnt lgkmcnt(0)" ::: "memory");
        __builtin_amdgcn_sched_barrier(0);

        int gidx = base + lrow;
        float w = -1.f; int id = 0x7fffffff;
        if (gidx < ncand) {
            id = cand ? cand[gidx] : gidx;
            int cnt = cand ? ccnt[gidx] : counts[gidx];
            w = (float)cnt / (1.f + expf(-(pvrow[lrow] + b2)));
        }
        for (int r = 0; r < NTOP; ++r) {
            float bw = w; int bid = id;
#pragma unroll
            for (int m = 1; m < 32; m <<= 1) {
                float ow = __shfl_xor(bw, m); int oid = __shfl_xor(bid, m);
                if (ow > bw || (ow == bw && oid < bid)) { bw = ow; bid = oid; }
            }
            if (w == bw && id == bid) w = -2.f;
            if (lane == r) { taw[tile * NTOP + r] = bw; tai[tile * NTOP + r] = bid; }
        }
    }
}

// ---------- k_init: zero ws-control | W fragment table | qctx (4-way) ----------
__global__ __launch_bounds__(64) void k_init(const int* __restrict__ qterms,
                                             const float* __restrict__ emb,
                                             const float* __restrict__ sW1,
                                             char* __restrict__ ws) {
    int* wsi = (int*)ws;
    float* qctx = (float*)(ws + 400064);
    unsigned short* wfH = (unsigned short*)(ws + 1111424);
    unsigned short* wfL = (unsigned short*)(ws + 1193344);
    const int t = threadIdx.x;
    const int b = blockIdx.x;

    // zero counts[100000] + ncA + flag + bar (indices 0..100002)
    for (int i = b * 64 + t; i < VOCABN + 3; i += 512 * 64) wsi[i] = 0;

    if (b < 4) {                       // qctx: 75 dims per block
        __shared__ int qid[NQ];
        if (t < NQ) qid[t] = qterms[t];
        __syncthreads();
        for (int d = t; d < 75; d += 64) {
            int dim = b * 75 + d;
            float s = 0.f;
            for (int q = 0; q < NQ; ++q) s += emb[(long)qid[q] * EMBD + dim];
            qctx[dim] = s * (1.0f / NQ);
        }
        return;
    }
    if (b < 84) {                      // W fragment table: 5120 builders
        int i = (b - 4) * 64 + t;
        int c = i >> 8;
        int rest = i & 255;
        int tile = rest >> 6;
        int l = rest & 63;
        int col = tile * 32 + (l & 31);
        int kbase = c * 16 + (l >> 5) * 8;
        unsigned int hw[8], lw[8];
#pragma unroll
        for (int j = 0; j < 8; ++j) {
            int k = kbase + j;
            unsigned int hi = 0, lo = 0;
            if (k < EMBD) {
                float f = sW1[(long)k * HID + col];
                unsigned int u = __float_as_uint(f);
                hi = u >> 16;
                float r = __uint_as_float(u & 0xffff0000u);
                lo = __float_as_uint(f - r) >> 16;
            }
            hw[j] = hi; lw[j] = lo;
        }
        long fo = ((long)(c * 4 + tile) * 64 + l) * 8;
        *(u32x4*)&wfH[fo] = (u32x4){hw[0] | (hw[1] << 16), hw[2] | (hw[3] << 16),
                                    hw[4] | (hw[5] << 16), hw[6] | (hw[7] << 16)};
        *(u32x4*)&wfL[fo] = (u32x4){lw[0] | (lw[1] << 16), lw[2] | (lw[3] << 16),
                                    lw[4] | (lw[5] << 16), lw[6] | (lw[7] << 16)};
    }
}

// ---------- k_mega: hist|qcb -> compact -> scoreA -> merge+flag -> fallback -> final ----------
__global__ __launch_bounds__(64) void k_mega(
        const int* __restrict__ fdocs, int nflat,
        const float* __restrict__ emb, const float* __restrict__ sW1,
        const float* __restrict__ sb1, const float* __restrict__ sW2,
        const float* __restrict__ sb2, const float* __restrict__ eW1,
        const float* __restrict__ eb1, const float* __restrict__ eW2,
        const float* __restrict__ eb2, char* __restrict__ ws,
        float* __restrict__ out) {
    int* counts = (int*)ws;
    int* ncA    = (int*)(ws + 400000);
    int* flagp  = (int*)(ws + 400004);
    int* bar    = (int*)(ws + 400008);
    float* qctx = (float*)(ws + 400064);
    float* qcb  = (float*)(ws + 401280);
    float* gtw  = (float*)(ws + 401792);
    int*   gti  = (int*)(ws + 401856);
    int* candA  = (int*)(ws + 402432);
    int* ccntA  = (int*)(ws + 577280);
    float* tawA = (float*)(ws + 752128);
    int*   taiA = (int*)(ws + 806768);
    float* tbw  = (float*)(ws + 861408);
    int*   tbi  = (int*)(ws + 986408);
    unsigned short* wfH = (unsigned short*)(ws + 1111424);
    unsigned short* wfL = (unsigned short*)(ws + 1193344);

    const int t = threadIdx.x;
    const int b = blockIdx.x;

    __shared__ float mw[64 * NTOP];
    __shared__ int   mid[64 * NTOP];
    __shared__ float pv[32];
    __shared__ float qcs[EMBD];
    __shared__ float em[EMBD], hbuf[HID];
    __shared__ int   top_id[NTOP];
    __shared__ int   s_nA, s_flag;

    // ---- P1: histogram (blocks 1..255) | qcb (block 0) ----
    if (b == 0) {
        for (int i = t; i < EMBD; i += 64) qcs[i] = qctx[i];
        __syncthreads();
        float a0 = 0.f, a1 = 0.f;
        for (int k = 0; k < EMBD; ++k) {
            float q = qcs[k];
            a0 += q * sW1[(long)(EMBD + k) * HID + t];
            a1 += q * sW1[(long)(EMBD + k) * HID + t + 64];
        }
        qcb[t] = a0 + sb1[t];
        qcb[t + 64] = a1 + sb1[t + 64];
    } else {
        for (int i = (b - 1) * 64 + t; i < nflat; i += 255 * 64)
            atomicAdd(&counts[fdocs[i]], 1);
    }
    gbar(bar, 1);

    // ---- P2: compact (count >= CMIN) ----
    for (int i = b * 64 + t; i < VOCABN; i += NBLK * 64) {
        int c = counts[i];
        if (c >= CMIN) {
            int p = atomicAdd(ncA, 1);
            if (p < CAPA) { candA[p] = i; ccntA[p] = c; }
        }
    }
    gbar(bar, 2);

    // ---- P3: score A-candidates ----
    if (t == 0) {
        int v = __hip_atomic_load(ncA, __ATOMIC_ACQUIRE, __HIP_MEMORY_SCOPE_AGENT);
        s_nA = v > CAPA ? CAPA : v;
    }
    __syncthreads();
    const int nA = s_nA;
    score_tiles(b, NBLK, emb, wfH, wfL, qcb, sW2, sb2[0],
                candA, ccntA, nullptr, nA, tawA, taiA, pv);
    gbar(bar, 3);

    // ---- P4: merge A (block 0) + flag ----
    if (b == 0) {
        int ntA = (nA + 31) >> 5;
#pragma unroll
        for (int n = 0; n < NTOP; ++n) { mw[t * NTOP + n] = -1.f; mid[t * NTOP + n] = 0x7fffffff; }
        for (int i = t; i < ntA * NTOP; i += 64)
            lds_insert(mw, mid, t, tawA[i], taiA[i]);
        for (int s = 32; s > 0; s >>= 1) {
            __syncthreads();
            if (t < s) {
                const int ta = t * NTOP, tb = (t + s) * NTOP;
                float ow[NTOP]; int oid[NTOP];
                int i = 0, j = 0;
#pragma unroll
                for (int n = 0; n < NTOP; ++n) {
                    float wa = mw[ta + i]; int ia = mid[ta + i];
                    float wb = mw[tb + j]; int ib = mid[tb + j];
                    if (tbetter(wa, ia, wb, ib)) { ow[n] = wa; oid[n] = ia; ++i; }
                    else                         { ow[n] = wb; oid[n] = ib; ++j; }
                }
#pragma unroll
                for (int n = 0; n < NTOP; ++n) { mw[ta + n] = ow[n]; mid[ta + n] = oid[n]; }
            }
        }
        __syncthreads();
        if (t < NTOP) { gtw[t] = mw[t]; gti[t] = mid[t]; }
        if (t == 0) *flagp = (mw[NTOP - 1] > (float)(CMIN - 1)) ? 1 : 0;
    }
    gbar(bar, 4);

    // ---- P5: conditional exact fallback (full vocab sweep, skipped w.h.p.) ----
    if (t == 0) s_flag = __hip_atomic_load(flagp, __ATOMIC_ACQUIRE, __HIP_MEMORY_SCOPE_AGENT);
    __syncthreads();
    if (!s_flag)
        score_tiles(b, NBLK, emb, wfH, wfL, qcb, sW2, sb2[0],
                    nullptr, nullptr, counts, VOCABN, tbw, tbi, pv);
    gbar(bar, 5);

    // ---- P6: final top-10 + expansion MLP (block 0) ----
    if (b != 0) return;
    if (s_flag) {
        if (t < NTOP) {
            top_id[t] = gti[t];
            out[EMBD + t] = (float)gti[t];
            out[EMBD + NTOP + t] = gtw[t];
        }
    } else {
#pragma unroll
        for (int n = 0; n < NTOP; ++n) { mw[t * NTOP + n] = -1.f; mid[t * NTOP + n] = 0x7fffffff; }
        for (int i = t; i < GRID_F * NTOP; i += 64)
            lds_insert(mw, mid, t, tbw[i], tbi[i]);
        for (int s = 32; s > 0; s >>= 1) {
            __syncthreads();
            if (t < s) {
                const int ta = t * NTOP, tb = (t + s) * NTOP;
                float ow[NTOP]; int oid[NTOP];
                int i = 0, j = 0;
#pragma unroll
                for (int n = 0; n < NTOP; ++n) {
                    float wa = mw[ta + i]; int ia = mid[ta + i];
                    float wb = mw[tb + j]; int ib = mid[tb + j];
                    if (tbetter(wa, ia, wb, ib)) { ow[n] = wa; oid[n] = ia; ++i; }
                    else                         { ow[n] = wb; oid[n] = ib; ++j; }
                }
#pragma unroll
                for (int n = 0; n < NTOP; ++n) { mw[ta + n] = ow[n]; mid[ta + n] = oid[n]; }
            }
        }
        __syncthreads();
        if (t < NTOP) {
            top_id[t] = mid[t];
            out[EMBD + t] = (float)mid[t];
            out[EMBD + NTOP + t] = mw[t];
        }
    }
    __syncthreads();

    // exp_mean + qctx into LDS
    for (int i = t; i < EMBD; i += 64) {
        float s = 0.f;
        for (int n = 0; n < NTOP; ++n) {
            long rid = top_id[n];
            if (rid > VOCABN - 1) rid = VOCABN - 1;
            s += emb[rid * EMBD + i];
        }
        em[i] = s * (1.0f / NTOP);
        qcs[i] = qctx[i];
    }
    __syncthreads();

    {   // h = relu(feat . eW1 + eb1); lane t covers cols t and t+64
        float a0 = 0.f, a1 = 0.f;
        for (int k = 0; k < EMBD; ++k) {
            float q = qcs[k], e = em[k], f = q * e;
            a0 += q * eW1[(long)k * HID + t]
                + e * eW1[(long)(EMBD + k) * HID + t]
                + f * eW1[(long)(2 * EMBD + k) * HID + t];
            a1 += q * eW1[(long)k * HID + t + 64]
                + e * eW1[(long)(EMBD + k) * HID + t + 64]
                + f * eW1[(long)(2 * EMBD + k) * HID + t + 64];
        }
        hbuf[t] = fmaxf(a0 + eb1[t], 0.f);
        hbuf[t + 64] = fmaxf(a1 + eb1[t + 64], 0.f);
    }
    __syncthreads();

    for (int i = t; i < EMBD; i += 64) {
        float a = eb2[i];
        for (int j = 0; j < HID; ++j) a += hbuf[j] * eW2[(long)j * EMBD + i];
        out[i] = a;
    }
}

extern "C" void kernel_launch(void* const* d_in, const int* in_sizes, int n_in,
                              void* d_out, int out_size, void* d_ws, size_t ws_size,
                              hipStream_t stream) {
    const int* qterms  = (const int*)d_in[0];
    const int* fdocs   = (const int*)d_in[1];
    const float* emb   = (const float*)d_in[3];
    const float* sW1   = (const float*)d_in[4];
    const float* sb1   = (const float*)d_in[5];
    const float* sW2   = (const float*)d_in[6];
    const float* sb2   = (const float*)d_in[7];
    const float* eW1   = (const float*)d_in[8];
    const float* eb1   = (const float*)d_in[9];
    const float* eW2   = (const float*)d_in[10];
    const float* eb2   = (const float*)d_in[11];
    char* ws = (char*)d_ws;
    float* out = (float*)d_out;

    int nflat = in_sizes[1];

    k_init<<<512, 64, 0, stream>>>(qterms, emb, sW1, ws);
    k_mega<<<NBLK, 64, 0, stream>>>(fdocs, nflat, emb, sW1, sb1, sW2, sb2,
                                    eW1, eb1, eW2, eb2, ws, out);
}

// Round 16
// 132.370 us; speedup vs baseline: 2.9213x; 2.9213x over previous
//
#include <hip/hip_runtime.h>
#include <math.h>

#define VOCABN 100000
#define EMBD 300
#define HID 128
#define NQ 32
#define NTOP 10

#define NCHS 19             // chunks scored, 16 k each (k 0..303, tail zero-padded)
#define CMIN 3
#define NBLK_AC 256
#define RANGE 391           // 256*391 = 100096 >= VOCABN
#define RANGE_ITERS 7       // ceil(391/64) -- uniform trip count for all lanes
#define RANGE_PAD 448       // >= ceil(RANGE/32)*32 + 32 (allw batch padding)
#define GRID_F ((VOCABN + 31) / 32)   // 3125 dense tiles (fallback)

typedef __attribute__((ext_vector_type(8))) short bf16x8;
typedef __attribute__((ext_vector_type(4))) float f32x4;
typedef __attribute__((ext_vector_type(16))) float f32x16;
typedef __attribute__((ext_vector_type(4))) unsigned int u32x4;

__device__ __forceinline__ void split8(const f32x4 a, const f32x4 b,
                                       u32x4* hi, u32x4* lo) {
    float ef[8] = {a.x, a.y, a.z, a.w, b.x, b.y, b.z, b.w};
    unsigned int hw[8], lw[8];
#pragma unroll
    for (int j = 0; j < 8; ++j) {
        unsigned int u = __float_as_uint(ef[j]);
        hw[j] = u >> 16;
        float r = __uint_as_float(u & 0xffff0000u);
        lw[j] = __float_as_uint(ef[j] - r) >> 16;
    }
    *hi = (u32x4){hw[0] | (hw[1] << 16), hw[2] | (hw[3] << 16),
                  hw[4] | (hw[5] << 16), hw[6] | (hw[7] << 16)};
    *lo = (u32x4){lw[0] | (lw[1] << 16), lw[2] | (lw[3] << 16),
                  lw[4] | (lw[5] << 16), lw[6] | (lw[7] << 16)};
}

__device__ __forceinline__ bool tbetter(float w1, int i1, float w2, int i2) {
    return w1 > w2 || (w1 == w2 && i1 < i2);
}

__device__ __forceinline__ void lds_insert(float* mw, int* mid, int t, float w, int id) {
    const int b = t * NTOP;
    if (!tbetter(w, id, mw[b + NTOP - 1], mid[b + NTOP - 1])) return;
    int p = NTOP - 1;
    while (p > 0 && tbetter(w, id, mw[b + p - 1], mid[b + p - 1])) {
        mw[b + p] = mw[b + p - 1]; mid[b + p] = mid[b + p - 1]; --p;
    }
    mw[b + p] = w; mid[b + p] = id;
}

// ---------- shared scorer macros (proven r7/r12 core) ----------
#define LOADC_CORE(NN, S)                                                    \
    { int nn_ = (NN);                                                        \
      if (nn_ < NCHS) {                                                      \
          int k0_ = nn_ * 16 + khalf * 8;                                    \
          e0[S] = (k0_ + 4 <= EMBD) ? *(const f32x4*)(ebase + k0_) : zf4;    \
          e1[S] = (k0_ + 8 <= EMBD) ? *(const f32x4*)(ebase + k0_ + 4) : zf4;\
          _Pragma("unroll")                                                  \
          for (int t_ = 0; t_ < 4; ++t_) {                                   \
              long fo_ = ((long)(nn_ * 4 + t_) * 64 + lane) * 8;             \
              wh[S][t_] = *(const u32x4*)&wfH[fo_];                          \
              wl[S][t_] = *(const u32x4*)&wfL[fo_];                          \
          } } }

#define COMP_CORE(CC, S)                                                     \
    { if ((CC) < NCHS) {                                                     \
          union { bf16x8 v; u32x4 u; } eh_, el_;                             \
          split8(e0[S], e1[S], &eh_.u, &el_.u);                              \
          _Pragma("unroll")                                                  \
          for (int t_ = 0; t_ < 4; ++t_) {                                   \
              union { bf16x8 v; u32x4 u; } bh_, bl_;                         \
              bh_.u = wh[S][t_]; bl_.u = wl[S][t_];                          \
              acc[t_] = __builtin_amdgcn_mfma_f32_32x32x16_bf16(eh_.v, bh_.v, acc[t_], 0, 0, 0); \
              acc[t_] = __builtin_amdgcn_mfma_f32_32x32x16_bf16(eh_.v, bl_.v, acc[t_], 0, 0, 0); \
              acc[t_] = __builtin_amdgcn_mfma_f32_32x32x16_bf16(el_.v, bh_.v, acc[t_], 0, 0, 0); \
          } } }

// full-tile scorer used only in the rare fallback (proven r12)
__device__ void score_tiles(int gw, int nwaves, const float* __restrict__ emb,
                            const unsigned short* __restrict__ wfH,
                            const unsigned short* __restrict__ wfL,
                            const float* __restrict__ qcbp,
                            const float* __restrict__ w2p, float b2,
                            const int* __restrict__ counts, int ncand,
                            float* __restrict__ taw, int* __restrict__ tai,
                            float* pvrow) {
    const int lane = threadIdx.x & 63;
    const int lrow = lane & 31;
    const int khalf = lane >> 5;
    const int ntile = (ncand + 31) >> 5;

    float qv[4], w2v[4];
#pragma unroll
    for (int t = 0; t < 4; ++t) {
        qv[t] = qcbp[t * 32 + lrow];
        w2v[t] = w2p[t * 32 + lrow];
    }

    for (int tile = gw; tile < ntile; tile += nwaves) {
        const int base = tile * 32;
        int ri = base + lrow;
        int rc = ri < ncand ? ri : ncand - 1;
        const float* ebase = emb + (long)rc * EMBD;

        f32x16 acc[4];
#pragma unroll
        for (int t = 0; t < 4; ++t)
#pragma unroll
            for (int r = 0; r < 16; ++r) acc[t][r] = 0.f;

        f32x4 e0[3], e1[3];
        u32x4 wh[3][4], wl[3][4];
        const f32x4 zf4 = (f32x4){0.f, 0.f, 0.f, 0.f};

        LOADC_CORE(0, 0) LOADC_CORE(1, 1) LOADC_CORE(2, 2)
        for (int g = 0; g < 7; ++g) {
            int c = g * 3;
            COMP_CORE(c + 0, 0) LOADC_CORE(c + 3, 0)
            COMP_CORE(c + 1, 1) LOADC_CORE(c + 4, 1)
            COMP_CORE(c + 2, 2) LOADC_CORE(c + 5, 2)
        }

        float pr[16];
#pragma unroll
        for (int r = 0; r < 16; ++r) {
            float s = 0.f;
#pragma unroll
            for (int t = 0; t < 4; ++t) {
                float h = fmaxf(acc[t][r] + qv[t], 0.f);
                s += h * w2v[t];
            }
            s += __shfl_xor(s, 1); s += __shfl_xor(s, 2);
            s += __shfl_xor(s, 4); s += __shfl_xor(s, 8);
            s += __shfl_xor(s, 16);
            pr[r] = s;
        }
        if (lrow == 0) {
#pragma unroll
            for (int r = 0; r < 16; ++r)
                pvrow[(r & 3) + 8 * (r >> 2) + 4 * khalf] = pr[r];
        }
        asm volatile("s_waitcnt lgkmcnt(0)" ::: "memory");
        __builtin_amdgcn_sched_barrier(0);

        int gidx = base + lrow;
        float w = -1.f; int id = 0x7fffffff;
        if (gidx < ncand) {
            id = gidx;
            w = (float)counts[gidx] / (1.f + expf(-(pvrow[lrow] + b2)));
        }
        for (int r = 0; r < NTOP; ++r) {
            float bw = w; int bid = id;
#pragma unroll
            for (int m = 1; m < 32; m <<= 1) {
                float ow = __shfl_xor(bw, m); int oid = __shfl_xor(bid, m);
                if (ow > bw || (ow == bw && oid < bid)) { bw = ow; bid = oid; }
            }
            if (w == bw && id == bid) w = -2.f;
            if (lane == r) { taw[tile * NTOP + r] = bw; tai[tile * NTOP + r] = bid; }
        }
    }
}

// ---------- k_init: zero counts | qctx | qcb | W fragment table ----------
__global__ __launch_bounds__(64) void k_init(const int* __restrict__ qterms,
                                             const float* __restrict__ emb,
                                             const float* __restrict__ sW1,
                                             const float* __restrict__ sb1,
                                             char* __restrict__ ws) {
    int* counts = (int*)ws;
    float* qctx = (float*)(ws + 400064);
    float* qcb  = (float*)(ws + 401280);
    unsigned short* wfH = (unsigned short*)(ws + 401920);
    unsigned short* wfL = (unsigned short*)(ws + 483840);
    const int t = threadIdx.x;
    const int b = blockIdx.x;

    for (int i = b * 64 + t; i < VOCABN; i += 512 * 64) counts[i] = 0;

    if (b < 4) {                       // qctx: 75 dims per block
        __shared__ int qid[NQ];
        if (t < NQ) qid[t] = qterms[t];
        __syncthreads();
        for (int d = t; d < 75; d += 64) {
            int dim = b * 75 + d;
            float s = 0.f;
            for (int q = 0; q < NQ; ++q) s += emb[(long)qid[q] * EMBD + dim];
            qctx[dim] = s * (1.0f / NQ);
        }
        return;
    }
    if (b == 4) {                      // qcb = sb1 + qctx . W1b (local qc recompute)
        __shared__ int qid[NQ];
        __shared__ float qc[EMBD];
        if (t < NQ) qid[t] = qterms[t];
        __syncthreads();
        for (int d = t; d < EMBD; d += 64) {
            float s = 0.f;
            for (int q = 0; q < NQ; ++q) s += emb[(long)qid[q] * EMBD + d];
            qc[d] = s * (1.0f / NQ);
        }
        __syncthreads();
        float a0 = 0.f, a1 = 0.f;
        for (int k = 0; k < EMBD; ++k) {
            float q = qc[k];
            a0 += q * sW1[(long)(EMBD + k) * HID + t];
            a1 += q * sW1[(long)(EMBD + k) * HID + t + 64];
        }
        qcb[t] = a0 + sb1[t];
        qcb[t + 64] = a1 + sb1[t + 64];
        return;
    }
    if (b < 85) {                      // W fragment table: 5120 builders
        int i = (b - 5) * 64 + t;
        int c = i >> 8;
        int rest = i & 255;
        int tile = rest >> 6;
        int l = rest & 63;
        int col = tile * 32 + (l & 31);
        int kbase = c * 16 + (l >> 5) * 8;
        unsigned int hw[8], lw[8];
#pragma unroll
        for (int j = 0; j < 8; ++j) {
            int k = kbase + j;
            unsigned int hi = 0, lo = 0;
            if (k < EMBD) {
                float f = sW1[(long)k * HID + col];
                unsigned int u = __float_as_uint(f);
                hi = u >> 16;
                float r = __uint_as_float(u & 0xffff0000u);
                lo = __float_as_uint(f - r) >> 16;
            }
            hw[j] = hi; lw[j] = lo;
        }
        long fo = ((long)(c * 4 + tile) * 64 + l) * 8;
        *(u32x4*)&wfH[fo] = (u32x4){hw[0] | (hw[1] << 16), hw[2] | (hw[3] << 16),
                                    hw[4] | (hw[5] << 16), hw[6] | (hw[7] << 16)};
        *(u32x4*)&wfL[fo] = (u32x4){lw[0] | (lw[1] << 16), lw[2] | (lw[3] << 16),
                                    lw[4] | (lw[5] << 16), lw[6] | (lw[7] << 16)};
    }
}

// ---------- k_hist: pure histogram ----------
__global__ __launch_bounds__(256) void k_hist(const int* __restrict__ fdocs, int n,
                                              int* __restrict__ counts) {
    for (int i = blockIdx.x * 256 + threadIdx.x; i < n; i += gridDim.x * 256)
        atomicAdd(&counts[fdocs[i]], 1);
}

// ---------- k_scoreAC: local compact (count>=CMIN) + batch MFMA score + wave top-10 ----------
__global__ __launch_bounds__(64) void k_scoreAC(
        const float* __restrict__ emb,
        const unsigned short* __restrict__ wfH,
        const unsigned short* __restrict__ wfL,
        const float* __restrict__ qcb,
        const float* __restrict__ sW2,
        const float* __restrict__ sb2,
        const int* __restrict__ counts,
        float* __restrict__ taw, int* __restrict__ tai) {
    const int lane = threadIdx.x;
    const int blk = blockIdx.x;
    const int lrow = lane & 31;
    const int khalf = lane >> 5;
    const int base0 = blk * RANGE;

    __shared__ int   cl_id[RANGE_PAD];
    __shared__ int   cl_cnt[RANGE_PAD];
    __shared__ float allw[RANGE_PAD];
    __shared__ float pv[32];

    // ---- ballot compaction, UNIFORM trip count (r15 bug: partial last iter
    // left lanes 7..63 with stale/divergent ncl; now all 64 lanes run all
    // RANGE_ITERS iterations with pred=false padding) ----
    int ncl = 0;
#pragma unroll
    for (int it = 0; it < RANGE_ITERS; ++it) {
        int i = it * 64 + lane;
        int v = base0 + i;
        int c = (i < RANGE && v < VOCABN) ? counts[v] : 0;
        bool pred = (c >= CMIN);
        unsigned long long m = __ballot(pred);
        int pos = ncl + __popcll(m & ((1ull << lane) - 1ull));
        if (pred) { cl_id[pos] = v; cl_cnt[pos] = c; }
        ncl += __popcll(m);
    }
    __syncthreads();

    float qv[4], w2v[4];
#pragma unroll
    for (int t = 0; t < 4; ++t) {
        qv[t] = qcb[t * 32 + lrow];
        w2v[t] = sW2[t * 32 + lrow];
    }
    const float b2 = sb2[0];

    // ---- batches of 32 candidates ----
    const int nb = (ncl + 31) >> 5;
    for (int bt = 0; bt < nb; ++bt) {
        int idx = bt * 32 + lrow;
        bool val = idx < ncl;
        int vrow = val ? cl_id[idx] : cl_id[0];
        const float* ebase = emb + (long)vrow * EMBD;

        f32x16 acc[4];
#pragma unroll
        for (int t = 0; t < 4; ++t)
#pragma unroll
            for (int r = 0; r < 16; ++r) acc[t][r] = 0.f;

        f32x4 e0[3], e1[3];
        u32x4 wh[3][4], wl[3][4];
        const f32x4 zf4 = (f32x4){0.f, 0.f, 0.f, 0.f};

        LOADC_CORE(0, 0) LOADC_CORE(1, 1) LOADC_CORE(2, 2)
        for (int g = 0; g < 7; ++g) {
            int c = g * 3;
            COMP_CORE(c + 0, 0) LOADC_CORE(c + 3, 0)
            COMP_CORE(c + 1, 1) LOADC_CORE(c + 4, 1)
            COMP_CORE(c + 2, 2) LOADC_CORE(c + 5, 2)
        }

        float pr[16];
#pragma unroll
        for (int r = 0; r < 16; ++r) {
            float s = 0.f;
#pragma unroll
            for (int t = 0; t < 4; ++t) {
                float h = fmaxf(acc[t][r] + qv[t], 0.f);
                s += h * w2v[t];
            }
            s += __shfl_xor(s, 1); s += __shfl_xor(s, 2);
            s += __shfl_xor(s, 4); s += __shfl_xor(s, 8);
            s += __shfl_xor(s, 16);
            pr[r] = s;
        }
        if (lrow == 0) {
#pragma unroll
            for (int r = 0; r < 16; ++r)
                pv[(r & 3) + 8 * (r >> 2) + 4 * khalf] = pr[r];
        }
        asm volatile("s_waitcnt lgkmcnt(0)" ::: "memory");
        __builtin_amdgcn_sched_barrier(0);

        float w = -1.f;
        if (val) w = (float)cl_cnt[idx] / (1.f + expf(-(pv[lrow] + b2)));
        allw[bt * 32 + lrow] = w;   // both lane halves write identical value
    }
    __syncthreads();

    // ---- wave top-10 over allw[0..ncl) with knockout ----
    for (int r = 0; r < NTOP; ++r) {
        float bw = -1.f; int bid = 0x7fffffff; int bslot = -1;
        for (int i = lane; i < ncl; i += 64) {
            float w = allw[i]; int id = cl_id[i];
            if (w > bw || (w == bw && id < bid)) { bw = w; bid = id; bslot = i; }
        }
#pragma unroll
        for (int m = 1; m < 64; m <<= 1) {
            float ow = __shfl_xor(bw, m);
            int oid = __shfl_xor(bid, m);
            int osl = __shfl_xor(bslot, m);
            if (ow > bw || (ow == bw && oid < bid)) { bw = ow; bid = oid; bslot = osl; }
        }
        if (lane == 0 && bslot >= 0) allw[bslot] = -2.f;
        if (lane == r) { taw[blk * NTOP + r] = bw; tai[blk * NTOP + r] = bid; }
        __syncthreads();
    }
}

// ---------- k_mergefinal: merge + flag + (MLP | rare dense fallback + MLP) ----------
__global__ __launch_bounds__(512) void k_mergefinal(
        const float* __restrict__ taw, const int* __restrict__ tai,
        const float* __restrict__ qctx, const float* __restrict__ emb,
        const unsigned short* __restrict__ wfH, const unsigned short* __restrict__ wfL,
        const float* __restrict__ qcb, const float* __restrict__ sW2,
        const float* __restrict__ sb2, const int* __restrict__ counts,
        const float* __restrict__ eW1, const float* __restrict__ eb1,
        const float* __restrict__ eW2, const float* __restrict__ eb2,
        float* __restrict__ tbw, int* __restrict__ tbi,
        float* __restrict__ out) {
    __shared__ float mw[512 * NTOP];
    __shared__ int   mid[512 * NTOP];
    __shared__ float pvs[8][32];
    __shared__ int   top_id[NTOP];
    __shared__ float qc[EMBD], em[EMBD], hbuf[HID];
    const int t = threadIdx.x;

    // merge A candidates (256 waves x 10)
#pragma unroll
    for (int n = 0; n < NTOP; ++n) { mw[t * NTOP + n] = -1.f; mid[t * NTOP + n] = 0x7fffffff; }
    for (int i = t; i < NBLK_AC * NTOP; i += 512)
        lds_insert(mw, mid, t, taw[i], tai[i]);
    for (int s = 256; s > 0; s >>= 1) {
        __syncthreads();
        if (t < s) {
            const int ta = t * NTOP, tb = (t + s) * NTOP;
            float ow[NTOP]; int oid[NTOP];
            int i = 0, j = 0;
#pragma unroll
            for (int n = 0; n < NTOP; ++n) {
                float wa = mw[ta + i]; int ia = mid[ta + i];
                float wb = mw[tb + j]; int ib = mid[tb + j];
                if (tbetter(wa, ia, wb, ib)) { ow[n] = wa; oid[n] = ia; ++i; }
                else                         { ow[n] = wb; oid[n] = ib; ++j; }
            }
#pragma unroll
            for (int n = 0; n < NTOP; ++n) { mw[ta + n] = ow[n]; mid[ta + n] = oid[n]; }
        }
    }
    __syncthreads();

    // exactness flag: excluded rows (count<=2) have weight = count*sigmoid < 2
    const bool flag = (mw[NTOP - 1] >= 2.0f);

    if (!flag) {
        // rare path: dense rescore of the full vocab by this block's 8 waves
        score_tiles(t >> 6, 8, emb, wfH, wfL, qcb, sW2, sb2[0],
                    counts, VOCABN, tbw, tbi, pvs[t >> 6]);
        __syncthreads();
#pragma unroll
        for (int n = 0; n < NTOP; ++n) { mw[t * NTOP + n] = -1.f; mid[t * NTOP + n] = 0x7fffffff; }
        for (int i = t; i < GRID_F * NTOP; i += 512)
            lds_insert(mw, mid, t, tbw[i], tbi[i]);
        for (int s = 256; s > 0; s >>= 1) {
            __syncthreads();
            if (t < s) {
                const int ta = t * NTOP, tb = (t + s) * NTOP;
                float ow[NTOP]; int oid[NTOP];
                int i = 0, j = 0;
#pragma unroll
                for (int n = 0; n < NTOP; ++n) {
                    float wa = mw[ta + i]; int ia = mid[ta + i];
                    float wb = mw[tb + j]; int ib = mid[tb + j];
                    if (tbetter(wa, ia, wb, ib)) { ow[n] = wa; oid[n] = ia; ++i; }
                    else                         { ow[n] = wb; oid[n] = ib; ++j; }
                }
#pragma unroll
                for (int n = 0; n < NTOP; ++n) { mw[ta + n] = ow[n]; mid[ta + n] = oid[n]; }
            }
        }
        __syncthreads();
    }

    if (t < NTOP) {
        top_id[t] = mid[t];
        out[EMBD + t] = (float)mid[t];
        out[EMBD + NTOP + t] = mw[t];
    }
    __syncthreads();

    for (int i = t; i < EMBD; i += 512) {
        float s = 0.f;
        for (int n = 0; n < NTOP; ++n) {
            long rid = top_id[n];
            if (rid > VOCABN - 1) rid = VOCABN - 1;   // sentinel clamp
            s += emb[rid * EMBD + i];
        }
        em[i] = s * (1.0f / NTOP);
        qc[i] = qctx[i];
    }
    __syncthreads();

    {   // h = relu(feat . eW1 + eb1); 4 threads per col, K split 75 (proven r12)
        int col = t >> 2, ks = t & 3;
        float a = 0.f;
        int k0 = ks * 75, k1 = k0 + 75;
        for (int k = k0; k < k1; ++k) {
            float q = qc[k], e = em[k];
            a += q * eW1[(long)k * HID + col];
            a += e * eW1[(long)(EMBD + k) * HID + col];
            a += (q * e) * eW1[(long)(2 * EMBD + k) * HID + col];
        }
        a += __shfl_xor(a, 1);
        a += __shfl_xor(a, 2);
        if (ks == 0) hbuf[col] = fmaxf(a + eb1[col], 0.f);
    }
    __syncthreads();

    for (int i = t; i < EMBD; i += 512) {
        float a = eb2[i];
        for (int j = 0; j < HID; ++j) a += hbuf[j] * eW2[(long)j * EMBD + i];
        out[i] = a;
    }
}

extern "C" void kernel_launch(void* const* d_in, const int* in_sizes, int n_in,
                              void* d_out, int out_size, void* d_ws, size_t ws_size,
                              hipStream_t stream) {
    const int* qterms  = (const int*)d_in[0];
    const int* fdocs   = (const int*)d_in[1];
    const float* emb   = (const float*)d_in[3];
    const float* sW1   = (const float*)d_in[4];
    const float* sb1   = (const float*)d_in[5];
    const float* sW2   = (const float*)d_in[6];
    const float* sb2   = (const float*)d_in[7];
    const float* eW1   = (const float*)d_in[8];
    const float* eb1   = (const float*)d_in[9];
    const float* eW2   = (const float*)d_in[10];
    const float* eb2   = (const float*)d_in[11];
    char* ws = (char*)d_ws;
    float* out = (float*)d_out;

    int*   counts = (int*)ws;                               // 400000
    float* qctx   = (float*)(ws + 400064);                  // 1200
    float* qcb    = (float*)(ws + 401280);                  // 512
    unsigned short* wfH = (unsigned short*)(ws + 401920);   // 81920
    unsigned short* wfL = (unsigned short*)(ws + 483840);   // 81920
    float* taw    = (float*)(ws + 565760);                  // 10240
    int*   tai    = (int*)(ws + 576000);                    // 10240
    float* tbw    = (float*)(ws + 586240);                  // 125000
    int*   tbi    = (int*)(ws + 711240);                    // 125000 -> 836240 total

    int nflat = in_sizes[1];

    k_init<<<512, 64, 0, stream>>>(qterms, emb, sW1, sb1, ws);
    k_hist<<<512, 256, 0, stream>>>(fdocs, nflat, counts);
    k_scoreAC<<<NBLK_AC, 64, 0, stream>>>(emb, wfH, wfL, qcb, sW2, sb2, counts, taw, tai);
    k_mergefinal<<<1, 512, 0, stream>>>(taw, tai, qctx, emb, wfH, wfL, qcb, sW2, sb2,
                                        counts, eW1, eb1, eW2, eb2, tbw, tbi, out);
}

// Round 17
// 118.395 us; speedup vs baseline: 3.2661x; 1.1180x over previous
//
#include <hip/hip_runtime.h>
#include <math.h>

#define VOCABN 100000
#define EMBD 300
#define HID 128
#define NQ 32
#define NTOP 10

#define NCHS 19             // chunks scored, 16 k each (k 0..303, tail zero-padded)
#define CMIN 3
#define NBLK_AC 2048
#define RANGE 49            // 2048*49 = 100352 >= VOCABN; <=64 -> single ballot iter
#define RANGE_PAD 64
#define GRID_F ((VOCABN + 31) / 32)   // 3125 dense tiles (fallback)

typedef __attribute__((ext_vector_type(8))) short bf16x8;
typedef __attribute__((ext_vector_type(4))) float f32x4;
typedef __attribute__((ext_vector_type(16))) float f32x16;
typedef __attribute__((ext_vector_type(4))) unsigned int u32x4;

__device__ __forceinline__ void split8(const f32x4 a, const f32x4 b,
                                       u32x4* hi, u32x4* lo) {
    float ef[8] = {a.x, a.y, a.z, a.w, b.x, b.y, b.z, b.w};
    unsigned int hw[8], lw[8];
#pragma unroll
    for (int j = 0; j < 8; ++j) {
        unsigned int u = __float_as_uint(ef[j]);
        hw[j] = u >> 16;
        float r = __uint_as_float(u & 0xffff0000u);
        lw[j] = __float_as_uint(ef[j] - r) >> 16;
    }
    *hi = (u32x4){hw[0] | (hw[1] << 16), hw[2] | (hw[3] << 16),
                  hw[4] | (hw[5] << 16), hw[6] | (hw[7] << 16)};
    *lo = (u32x4){lw[0] | (lw[1] << 16), lw[2] | (lw[3] << 16),
                  lw[4] | (lw[5] << 16), lw[6] | (lw[7] << 16)};
}

__device__ __forceinline__ bool tbetter(float w1, int i1, float w2, int i2) {
    return w1 > w2 || (w1 == w2 && i1 < i2);
}

__device__ __forceinline__ void lds_insert(float* mw, int* mid, int t, float w, int id) {
    const int b = t * NTOP;
    if (!tbetter(w, id, mw[b + NTOP - 1], mid[b + NTOP - 1])) return;
    int p = NTOP - 1;
    while (p > 0 && tbetter(w, id, mw[b + p - 1], mid[b + p - 1])) {
        mw[b + p] = mw[b + p - 1]; mid[b + p] = mid[b + p - 1]; --p;
    }
    mw[b + p] = w; mid[b + p] = id;
}

// ---------- depth-2 scorer macros (r11 variant: 72 VGPR, no spill) ----------
#define LOADC_CORE(NN, S)                                                    \
    { int nn_ = (NN);                                                        \
      if (nn_ < NCHS) {                                                      \
          int k0_ = nn_ * 16 + khalf * 8;                                    \
          e0[S] = (k0_ + 4 <= EMBD) ? *(const f32x4*)(ebase + k0_) : zf4;    \
          e1[S] = (k0_ + 8 <= EMBD) ? *(const f32x4*)(ebase + k0_ + 4) : zf4;\
          _Pragma("unroll")                                                  \
          for (int t_ = 0; t_ < 4; ++t_) {                                   \
              long fo_ = ((long)(nn_ * 4 + t_) * 64 + lane) * 8;             \
              wh[S][t_] = *(const u32x4*)&wfH[fo_];                          \
              wl[S][t_] = *(const u32x4*)&wfL[fo_];                          \
          } } }

#define COMP_CORE(CC, S)                                                     \
    { if ((CC) < NCHS) {                                                     \
          union { bf16x8 v; u32x4 u; } eh_, el_;                             \
          split8(e0[S], e1[S], &eh_.u, &el_.u);                              \
          _Pragma("unroll")                                                  \
          for (int t_ = 0; t_ < 4; ++t_) {                                   \
              union { bf16x8 v; u32x4 u; } bh_, bl_;                         \
              bh_.u = wh[S][t_]; bl_.u = wl[S][t_];                          \
              acc[t_] = __builtin_amdgcn_mfma_f32_32x32x16_bf16(eh_.v, bh_.v, acc[t_], 0, 0, 0); \
              acc[t_] = __builtin_amdgcn_mfma_f32_32x32x16_bf16(eh_.v, bl_.v, acc[t_], 0, 0, 0); \
              acc[t_] = __builtin_amdgcn_mfma_f32_32x32x16_bf16(el_.v, bh_.v, acc[t_], 0, 0, 0); \
          } } }

// scoring body for one 32-row batch: fills pv[0..31] with W2-reduced row sums
#define SCORE_BATCH_BODY                                                     \
    {                                                                        \
        f32x16 acc[4];                                                       \
        _Pragma("unroll")                                                    \
        for (int t_ = 0; t_ < 4; ++t_)                                       \
            _Pragma("unroll")                                                \
            for (int r_ = 0; r_ < 16; ++r_) acc[t_][r_] = 0.f;               \
        f32x4 e0[2], e1[2];                                                  \
        u32x4 wh[2][4], wl[2][4];                                            \
        const f32x4 zf4 = (f32x4){0.f, 0.f, 0.f, 0.f};                       \
        LOADC_CORE(0, 0) LOADC_CORE(1, 1)                                    \
        for (int g_ = 0; g_ < 10; ++g_) {                                    \
            const int c_ = g_ * 2;                                           \
            COMP_CORE(c_ + 0, 0) LOADC_CORE(c_ + 2, 0)                       \
            COMP_CORE(c_ + 1, 1) LOADC_CORE(c_ + 3, 1)                       \
        }                                                                    \
        float pr[16];                                                        \
        _Pragma("unroll")                                                    \
        for (int r_ = 0; r_ < 16; ++r_) {                                    \
            float s_ = 0.f;                                                  \
            _Pragma("unroll")                                                \
            for (int t_ = 0; t_ < 4; ++t_) {                                 \
                float h_ = fmaxf(acc[t_][r_] + qv[t_], 0.f);                 \
                s_ += h_ * w2v[t_];                                          \
            }                                                                \
            s_ += __shfl_xor(s_, 1); s_ += __shfl_xor(s_, 2);                \
            s_ += __shfl_xor(s_, 4); s_ += __shfl_xor(s_, 8);                \
            s_ += __shfl_xor(s_, 16);                                        \
            pr[r_] = s_;                                                     \
        }                                                                    \
        if (lrow == 0) {                                                     \
            _Pragma("unroll")                                                \
            for (int r_ = 0; r_ < 16; ++r_)                                  \
                pv[(r_ & 3) + 8 * (r_ >> 2) + 4 * khalf] = pr[r_];           \
        }                                                                    \
        asm volatile("s_waitcnt lgkmcnt(0)" ::: "memory");                   \
        __builtin_amdgcn_sched_barrier(0);                                   \
    }

// full-tile scorer used only in the rare fallback (proven r12)
__device__ void score_tiles(int gw, int nwaves, const float* __restrict__ emb,
                            const unsigned short* __restrict__ wfH,
                            const unsigned short* __restrict__ wfL,
                            const float* __restrict__ qcbp,
                            const float* __restrict__ w2p, float b2,
                            const int* __restrict__ counts, int ncand,
                            float* __restrict__ taw, int* __restrict__ tai,
                            float* pv) {
    const int lane = threadIdx.x & 63;
    const int lrow = lane & 31;
    const int khalf = lane >> 5;
    const int ntile = (ncand + 31) >> 5;

    float qv[4], w2v[4];
#pragma unroll
    for (int t = 0; t < 4; ++t) {
        qv[t] = qcbp[t * 32 + lrow];
        w2v[t] = w2p[t * 32 + lrow];
    }

    for (int tile = gw; tile < ntile; tile += nwaves) {
        const int base = tile * 32;
        int ri = base + lrow;
        int rc = ri < ncand ? ri : ncand - 1;
        const float* ebase = emb + (long)rc * EMBD;

        SCORE_BATCH_BODY

        int gidx = base + lrow;
        float w = -1.f; int id = 0x7fffffff;
        if (gidx < ncand) {
            id = gidx;
            w = (float)counts[gidx] / (1.f + expf(-(pv[lrow] + b2)));
        }
        for (int r = 0; r < NTOP; ++r) {
            float bw = w; int bid = id;
#pragma unroll
            for (int m = 1; m < 32; m <<= 1) {
                float ow = __shfl_xor(bw, m); int oid = __shfl_xor(bid, m);
                if (ow > bw || (ow == bw && oid < bid)) { bw = ow; bid = oid; }
            }
            if (w == bw && id == bid) w = -2.f;
            if (lane == r) { taw[tile * NTOP + r] = bw; tai[tile * NTOP + r] = bid; }
        }
    }
}

// ---------- k_init: zero counts | qctx | qcb | W fragment table ----------
__global__ __launch_bounds__(64) void k_init(const int* __restrict__ qterms,
                                             const float* __restrict__ emb,
                                             const float* __restrict__ sW1,
                                             const float* __restrict__ sb1,
                                             char* __restrict__ ws) {
    int* counts = (int*)ws;
    float* qctx = (float*)(ws + 400064);
    float* qcb  = (float*)(ws + 401280);
    unsigned short* wfH = (unsigned short*)(ws + 401920);
    unsigned short* wfL = (unsigned short*)(ws + 483840);
    const int t = threadIdx.x;
    const int b = blockIdx.x;

    for (int i = b * 64 + t; i < VOCABN; i += 512 * 64) counts[i] = 0;

    if (b < 4) {                       // qctx: 75 dims per block
        __shared__ int qid[NQ];
        if (t < NQ) qid[t] = qterms[t];
        __syncthreads();
        for (int d = t; d < 75; d += 64) {
            int dim = b * 75 + d;
            float s = 0.f;
            for (int q = 0; q < NQ; ++q) s += emb[(long)qid[q] * EMBD + dim];
            qctx[dim] = s * (1.0f / NQ);
        }
        return;
    }
    if (b == 4) {                      // qcb = sb1 + qctx . W1b (local qc recompute)
        __shared__ int qid[NQ];
        __shared__ float qc[EMBD];
        if (t < NQ) qid[t] = qterms[t];
        __syncthreads();
        for (int d = t; d < EMBD; d += 64) {
            float s = 0.f;
            for (int q = 0; q < NQ; ++q) s += emb[(long)qid[q] * EMBD + d];
            qc[d] = s * (1.0f / NQ);
        }
        __syncthreads();
        float a0 = 0.f, a1 = 0.f;
        for (int k = 0; k < EMBD; ++k) {
            float q = qc[k];
            a0 += q * sW1[(long)(EMBD + k) * HID + t];
            a1 += q * sW1[(long)(EMBD + k) * HID + t + 64];
        }
        qcb[t] = a0 + sb1[t];
        qcb[t + 64] = a1 + sb1[t + 64];
        return;
    }
    if (b < 85) {                      // W fragment table: 5120 builders
        int i = (b - 5) * 64 + t;
        int c = i >> 8;
        int rest = i & 255;
        int tile = rest >> 6;
        int l = rest & 63;
        int col = tile * 32 + (l & 31);
        int kbase = c * 16 + (l >> 5) * 8;
        unsigned int hw[8], lw[8];
#pragma unroll
        for (int j = 0; j < 8; ++j) {
            int k = kbase + j;
            unsigned int hi = 0, lo = 0;
            if (k < EMBD) {
                float f = sW1[(long)k * HID + col];
                unsigned int u = __float_as_uint(f);
                hi = u >> 16;
                float r = __uint_as_float(u & 0xffff0000u);
                lo = __float_as_uint(f - r) >> 16;
            }
            hw[j] = hi; lw[j] = lo;
        }
        long fo = ((long)(c * 4 + tile) * 64 + l) * 8;
        *(u32x4*)&wfH[fo] = (u32x4){hw[0] | (hw[1] << 16), hw[2] | (hw[3] << 16),
                                    hw[4] | (hw[5] << 16), hw[6] | (hw[7] << 16)};
        *(u32x4*)&wfL[fo] = (u32x4){lw[0] | (lw[1] << 16), lw[2] | (lw[3] << 16),
                                    lw[4] | (lw[5] << 16), lw[6] | (lw[7] << 16)};
    }
}

// ---------- k_hist: pure histogram ----------
__global__ __launch_bounds__(256) void k_hist(const int* __restrict__ fdocs, int n,
                                              int* __restrict__ counts) {
    for (int i = blockIdx.x * 256 + threadIdx.x; i < n; i += gridDim.x * 256)
        atomicAdd(&counts[fdocs[i]], 1);
}

// ---------- k_scoreAC: 49-row range compact + <=2 batch MFMA score + wave top-10 ----------
__global__ __launch_bounds__(64) void k_scoreAC(
        const float* __restrict__ emb,
        const unsigned short* __restrict__ wfH,
        const unsigned short* __restrict__ wfL,
        const float* __restrict__ qcb,
        const float* __restrict__ sW2,
        const float* __restrict__ sb2,
        const int* __restrict__ counts,
        float* __restrict__ taw, int* __restrict__ tai) {
    const int lane = threadIdx.x;
    const int blk = blockIdx.x;
    const int lrow = lane & 31;
    const int khalf = lane >> 5;
    const int base0 = blk * RANGE;

    __shared__ int   cl_id[RANGE_PAD];
    __shared__ int   cl_cnt[RANGE_PAD];
    __shared__ float allw[RANGE_PAD];
    __shared__ float pv[32];

    // ---- single-iteration ballot compaction (RANGE <= 64, uniform trip) ----
    int v = base0 + lane;
    int c = (lane < RANGE && v < VOCABN) ? counts[v] : 0;
    bool pred = (c >= CMIN);
    unsigned long long m = __ballot(pred);
    if (pred) {
        int pos = __popcll(m & ((1ull << lane) - 1ull));
        cl_id[pos] = v; cl_cnt[pos] = c;
    }
    const int ncl = __popcll(m);
    __syncthreads();

    if (ncl == 0) {
        if (lane < NTOP) { taw[blk * NTOP + lane] = -1.f; tai[blk * NTOP + lane] = 0x7fffffff; }
        return;
    }

    float qv[4], w2v[4];
#pragma unroll
    for (int t = 0; t < 4; ++t) {
        qv[t] = qcb[t * 32 + lrow];
        w2v[t] = sW2[t * 32 + lrow];
    }
    const float b2 = sb2[0];

    // ---- up to 2 batches of 32 candidates ----
    const int nb = (ncl + 31) >> 5;
    for (int bt = 0; bt < nb; ++bt) {
        int idx = bt * 32 + lrow;
        bool val = idx < ncl;
        int vrow = val ? cl_id[idx] : cl_id[0];
        const float* ebase = emb + (long)vrow * EMBD;

        SCORE_BATCH_BODY

        float w = -1.f;
        if (val) w = (float)cl_cnt[idx] / (1.f + expf(-(pv[lrow] + b2)));
        allw[bt * 32 + lrow] = w;   // both lane halves write identical value
        __syncthreads();
    }

    // ---- wave top-10 over allw[0..ncl) with knockout ----
    for (int r = 0; r < NTOP; ++r) {
        float bw = -1.f; int bid = 0x7fffffff; int bslot = -1;
        if (lane < ncl) { bw = allw[lane]; bid = cl_id[lane]; bslot = lane; }
#pragma unroll
        for (int mm = 1; mm < 64; mm <<= 1) {
            float ow = __shfl_xor(bw, mm);
            int oid = __shfl_xor(bid, mm);
            int osl = __shfl_xor(bslot, mm);
            if (ow > bw || (ow == bw && oid < bid)) { bw = ow; bid = oid; bslot = osl; }
        }
        if (lane == 0 && bslot >= 0) allw[bslot] = -2.f;
        if (lane == r) { taw[blk * NTOP + r] = bw; tai[blk * NTOP + r] = bid; }
        __syncthreads();
    }
}

// ---------- k_mergefinal: merge + flag + (MLP | rare dense fallback + MLP) ----------
__global__ __launch_bounds__(512) void k_mergefinal(
        const float* __restrict__ taw, const int* __restrict__ tai,
        const float* __restrict__ qctx, const float* __restrict__ emb,
        const unsigned short* __restrict__ wfH, const unsigned short* __restrict__ wfL,
        const float* __restrict__ qcb, const float* __restrict__ sW2,
        const float* __restrict__ sb2, const int* __restrict__ counts,
        const float* __restrict__ eW1, const float* __restrict__ eb1,
        const float* __restrict__ eW2, const float* __restrict__ eb2,
        float* __restrict__ tbw, int* __restrict__ tbi,
        float* __restrict__ out) {
    __shared__ float mw[512 * NTOP];
    __shared__ int   mid[512 * NTOP];
    __shared__ float pvs[8][32];
    __shared__ int   top_id[NTOP];
    __shared__ float qc[EMBD], em[EMBD], hbuf[HID];
    const int t = threadIdx.x;

    // merge A candidates (2048 blocks x 10)
#pragma unroll
    for (int n = 0; n < NTOP; ++n) { mw[t * NTOP + n] = -1.f; mid[t * NTOP + n] = 0x7fffffff; }
    for (int i = t; i < NBLK_AC * NTOP; i += 512)
        lds_insert(mw, mid, t, taw[i], tai[i]);
    for (int s = 256; s > 0; s >>= 1) {
        __syncthreads();
        if (t < s) {
            const int ta = t * NTOP, tb = (t + s) * NTOP;
            float ow[NTOP]; int oid[NTOP];
            int i = 0, j = 0;
#pragma unroll
            for (int n = 0; n < NTOP; ++n) {
                float wa = mw[ta + i]; int ia = mid[ta + i];
                float wb = mw[tb + j]; int ib = mid[tb + j];
                if (tbetter(wa, ia, wb, ib)) { ow[n] = wa; oid[n] = ia; ++i; }
                else                         { ow[n] = wb; oid[n] = ib; ++j; }
            }
#pragma unroll
            for (int n = 0; n < NTOP; ++n) { mw[ta + n] = ow[n]; mid[ta + n] = oid[n]; }
        }
    }
    __syncthreads();

    // exactness flag: excluded rows (count<=2) have weight = count*sigmoid < 2
    const bool flag = (mw[NTOP - 1] >= 2.0f);

    if (!flag) {
        // rare path: dense rescore of the full vocab by this block's 8 waves
        score_tiles(t >> 6, 8, emb, wfH, wfL, qcb, sW2, sb2[0],
                    counts, VOCABN, tbw, tbi, pvs[t >> 6]);
        __syncthreads();
#pragma unroll
        for (int n = 0; n < NTOP; ++n) { mw[t * NTOP + n] = -1.f; mid[t * NTOP + n] = 0x7fffffff; }
        for (int i = t; i < GRID_F * NTOP; i += 512)
            lds_insert(mw, mid, t, tbw[i], tbi[i]);
        for (int s = 256; s > 0; s >>= 1) {
            __syncthreads();
            if (t < s) {
                const int ta = t * NTOP, tb = (t + s) * NTOP;
                float ow[NTOP]; int oid[NTOP];
                int i = 0, j = 0;
#pragma unroll
                for (int n = 0; n < NTOP; ++n) {
                    float wa = mw[ta + i]; int ia = mid[ta + i];
                    float wb = mw[tb + j]; int ib = mid[tb + j];
                    if (tbetter(wa, ia, wb, ib)) { ow[n] = wa; oid[n] = ia; ++i; }
                    else                         { ow[n] = wb; oid[n] = ib; ++j; }
                }
#pragma unroll
                for (int n = 0; n < NTOP; ++n) { mw[ta + n] = ow[n]; mid[ta + n] = oid[n]; }
            }
        }
        __syncthreads();
    }

    if (t < NTOP) {
        top_id[t] = mid[t];
        out[EMBD + t] = (float)mid[t];
        out[EMBD + NTOP + t] = mw[t];
    }
    __syncthreads();

    for (int i = t; i < EMBD; i += 512) {
        float s = 0.f;
        for (int n = 0; n < NTOP; ++n) {
            long rid = top_id[n];
            if (rid > VOCABN - 1) rid = VOCABN - 1;   // sentinel clamp
            s += emb[rid * EMBD + i];
        }
        em[i] = s * (1.0f / NTOP);
        qc[i] = qctx[i];
    }
    __syncthreads();

    {   // h = relu(feat . eW1 + eb1); 4 threads per col, K split 75 (proven r12)
        int col = t >> 2, ks = t & 3;
        float a = 0.f;
        int k0 = ks * 75, k1 = k0 + 75;
        for (int k = k0; k < k1; ++k) {
            float q = qc[k], e = em[k];
            a += q * eW1[(long)k * HID + col];
            a += e * eW1[(long)(EMBD + k) * HID + col];
            a += (q * e) * eW1[(long)(2 * EMBD + k) * HID + col];
        }
        a += __shfl_xor(a, 1);
        a += __shfl_xor(a, 2);
        if (ks == 0) hbuf[col] = fmaxf(a + eb1[col], 0.f);
    }
    __syncthreads();

    for (int i = t; i < EMBD; i += 512) {
        float a = eb2[i];
        for (int j = 0; j < HID; ++j) a += hbuf[j] * eW2[(long)j * EMBD + i];
        out[i] = a;
    }
}

extern "C" void kernel_launch(void* const* d_in, const int* in_sizes, int n_in,
                              void* d_out, int out_size, void* d_ws, size_t ws_size,
                              hipStream_t stream) {
    const int* qterms  = (const int*)d_in[0];
    const int* fdocs   = (const int*)d_in[1];
    const float* emb   = (const float*)d_in[3];
    const float* sW1   = (const float*)d_in[4];
    const float* sb1   = (const float*)d_in[5];
    const float* sW2   = (const float*)d_in[6];
    const float* sb2   = (const float*)d_in[7];
    const float* eW1   = (const float*)d_in[8];
    const float* eb1   = (const float*)d_in[9];
    const float* eW2   = (const float*)d_in[10];
    const float* eb2   = (const float*)d_in[11];
    char* ws = (char*)d_ws;
    float* out = (float*)d_out;

    int*   counts = (int*)ws;                               // 400000
    float* qctx   = (float*)(ws + 400064);                  // 1200
    float* qcb    = (float*)(ws + 401280);                  // 512
    unsigned short* wfH = (unsigned short*)(ws + 401920);   // 81920
    unsigned short* wfL = (unsigned short*)(ws + 483840);   // 81920
    float* taw    = (float*)(ws + 565760);                  // 2048*10*4 = 81920
    int*   tai    = (int*)(ws + 647680);                    // 81920
    float* tbw    = (float*)(ws + 729600);                  // 125000
    int*   tbi    = (int*)(ws + 854600);                    // 125000 -> 979600 total

    int nflat = in_sizes[1];

    k_init<<<512, 64, 0, stream>>>(qterms, emb, sW1, sb1, ws);
    k_hist<<<512, 256, 0, stream>>>(fdocs, nflat, counts);
    k_scoreAC<<<NBLK_AC, 64, 0, stream>>>(emb, wfH, wfL, qcb, sW2, sb2, counts, taw, tai);
    k_mergefinal<<<1, 512, 0, stream>>>(taw, tai, qctx, emb, wfH, wfL, qcb, sW2, sb2,
                                        counts, eW1, eb1, eW2, eb2, tbw, tbi, out);
}